// Round 4
// baseline (6798.541 us; speedup 1.0000x reference)
//
#include <hip/hip_runtime.h>
#include <stdint.h>

#define N_NODES 50000
#define N_EDGES 200000
#define H 32
#define T_STEPS 8

typedef __attribute__((ext_vector_type(4))) float v4f;
typedef __attribute__((ext_vector_type(8))) _Float16 h8;

#define LO_SCALE 4096.0f
#define LO_DESCALE 2.44140625e-4f  // 1/4096

__device__ __forceinline__ uint32_t packh2(_Float16 a, _Float16 b) {
  return (uint32_t)__builtin_bit_cast(unsigned short, a) |
         ((uint32_t)__builtin_bit_cast(unsigned short, b) << 16);
}

// hid[e][d] = relu(edge_data[e].W1[d] + b1[d]), split into fp16 hi + scaled-lo.
__global__ void hidb_kernel(const float* __restrict__ ed, const float* __restrict__ W1,
                            const float* __restrict__ b1,
                            uint32_t* __restrict__ hidh, uint32_t* __restrict__ hidl) {
  int idx = blockIdx.x * blockDim.x + threadIdx.x;   // E*32 threads
  int e = idx >> 5, d2 = idx & 31;
  int d0 = d2 * 2;
  const float4* er = (const float4*)(ed + (size_t)e * 16);
  const float4* w0 = (const float4*)(W1 + (size_t)d0 * 16);
  const float4* w1 = (const float4*)(W1 + (size_t)(d0 + 1) * 16);
  float a0 = b1[d0], a1 = b1[d0 + 1];
#pragma unroll
  for (int k = 0; k < 4; k++) {
    float4 h = er[k], u = w0[k], v = w1[k];
    a0 += h.x * u.x + h.y * u.y + h.z * u.z + h.w * u.w;
    a1 += h.x * v.x + h.y * v.y + h.z * v.z + h.w * v.w;
  }
  a0 = fmaxf(a0, 0.f);
  a1 = fmaxf(a1, 0.f);
  _Float16 h0 = (_Float16)a0, h1 = (_Float16)a1;
  _Float16 l0 = (_Float16)((a0 - (float)h0) * LO_SCALE);
  _Float16 l1 = (_Float16)((a1 - (float)h1) * LO_SCALE);
  hidh[idx] = packh2(h0, h1);   // halfs: hid[e][d0], hid[e][d0+1]
  hidl[idx] = packh2(l0, l1);
}

// Pack W2 (1024x64 f32) into MFMA A-fragment-linear fp16 hi / scaled-lo layouts.
// chunk c = mtg*2 + kh; within chunk, lane l owns 16B:
//   W2[mtg*16 + (l&15)][kh*32 + (l>>4)*8 + 0..7].  32768 uint32 each (128 KB).
__global__ void w2pack_kernel(const float* __restrict__ W2,
                              uint32_t* __restrict__ W2Fh, uint32_t* __restrict__ W2Fl) {
  int o = blockIdx.x * blockDim.x + threadIdx.x;   // 32768 threads
  int c = o >> 8, u = o & 255;
  int lane = u >> 2, pr = u & 3;
  int mtg = c >> 1, kh = c & 1;
  int row = mtg * 16 + (lane & 15);
  int k = kh * 32 + (lane >> 4) * 8 + pr * 2;
  float v0 = W2[(size_t)row * 64 + k];
  float v1 = W2[(size_t)row * 64 + k + 1];
  _Float16 h0 = (_Float16)v0, h1 = (_Float16)v1;
  _Float16 l0 = (_Float16)((v0 - (float)h0) * LO_SCALE);
  _Float16 l1 = (_Float16)((v1 - (float)h1) * LO_SCALE);
  W2Fh[o] = packh2(h0, h1);
  W2Fl[o] = packh2(l0, l1);
}

// Fused message kernel with ~f32 A via fp16x2 split:
//   A = relu(Wh.hh + 2^-12*(Wh.hl_s + Wl_s.hh) + b2)   (element err ~3e-7)
// blockIdx&3 selects M-quarter (256 q-rows = 8 output i's); grid-stride over
// 64-edge groups.
__global__ __launch_bounds__(256, 2) void msg_kernel(
    const uint32_t* __restrict__ W2Fh, const uint32_t* __restrict__ W2Fl,
    const uint32_t* __restrict__ hidh, const uint32_t* __restrict__ hidl,
    const float* __restrict__ b2, const float* __restrict__ x,
    const int* __restrict__ edges, float* __restrict__ m) {
  __shared__ uint32_t w2h[8192];   // 32 KB: this block's M-quarter, hi
  __shared__ uint32_t w2l[8192];   // 32 KB: scaled lo
  __shared__ float b2s[256];
  int t = threadIdx.x;
  int mq = blockIdx.x & 3;
  for (int p = t; p < 8192; p += 256) {
    w2h[p] = W2Fh[mq * 8192 + p];
    w2l[p] = W2Fl[mq * 8192 + p];
  }
  b2s[t] = b2[mq * 256 + t];
  __syncthreads();

  int wv = t >> 6, lane = t & 63;
  int el = lane & 15, kg = lane >> 4;
  const h8* sh = (const h8*)w2h;       // fragment index = chunk*64 + lane
  const h8* sl = (const h8*)w2l;
  const h8* hbh = (const h8*)hidh;     // fragment index = e*8 + (khalf*4) + kg
  const h8* hbl = (const h8*)hidl;

  for (int es = (int)(blockIdx.x >> 2); es < N_EDGES / 64; es += 256) {
    int e = es * 64 + wv * 16 + el;
    int src = edges[2 * e], dst = edges[2 * e + 1];
    // B-fragments (hid^T): lane holds hid[e][kh*32 + kg*8 + 0..7]
    h8 bh0 = hbh[(size_t)e * 8 + kg];
    h8 bh1 = hbh[(size_t)e * 8 + 4 + kg];
    h8 bl0 = hbl[(size_t)e * 8 + kg];
    h8 bl1 = hbl[(size_t)e * 8 + 4 + kg];
    // x values needed in the epilogue: j = (mt&1)*16 + kg*4 + r
    v4f xr0 = *(const v4f*)(x + (size_t)src * 32 + kg * 4);
    v4f xr1 = *(const v4f*)(x + (size_t)src * 32 + 16 + kg * 4);

#pragma unroll
    for (int mp = 0; mp < 8; mp++) {
      float tacc = 0.f;
#pragma unroll
      for (int tp = 0; tp < 2; tp++) {
        int mt = 2 * mp + tp;
        h8 ah0 = sh[(size_t)(mt * 2 + 0) * 64 + lane];
        h8 ah1 = sh[(size_t)(mt * 2 + 1) * 64 + lane];
        h8 al0 = sl[(size_t)(mt * 2 + 0) * 64 + lane];
        h8 al1 = sl[(size_t)(mt * 2 + 1) * 64 + lane];
        v4f chi = *(const v4f*)(b2s + mt * 16 + kg * 4);   // bias as C-init
        chi = __builtin_amdgcn_mfma_f32_16x16x32_f16(ah0, bh0, chi, 0, 0, 0);
        chi = __builtin_amdgcn_mfma_f32_16x16x32_f16(ah1, bh1, chi, 0, 0, 0);
        v4f clo = {0.f, 0.f, 0.f, 0.f};
        clo = __builtin_amdgcn_mfma_f32_16x16x32_f16(ah0, bl0, clo, 0, 0, 0);
        clo = __builtin_amdgcn_mfma_f32_16x16x32_f16(ah1, bl1, clo, 0, 0, 0);
        clo = __builtin_amdgcn_mfma_f32_16x16x32_f16(al0, bh0, clo, 0, 0, 0);
        clo = __builtin_amdgcn_mfma_f32_16x16x32_f16(al1, bh1, clo, 0, 0, 0);
        v4f xr = tp ? xr1 : xr0;
#pragma unroll
        for (int r = 0; r < 4; r++) {
          float av = fmaxf(fmaf(clo[r], LO_DESCALE, chi[r]), 0.f);
          tacc = fmaf(av, xr[r], tacc);
        }
      }
      // tacc = partial msg[e][i] over this lane's 8 j's; reduce across kg
      float s = tacc;
      s += __shfl_xor(s, 16, 64);
      s += __shfl_xor(s, 32, 64);
      if (lane < 16) {
        int i = mq * 8 + mp;
        atomicAdd(&m[(size_t)src * 32 + i], s);
        if (src != dst) atomicAdd(&m[(size_t)dst * 32 + i], s);
      }
    }
  }
}

// GRU cell: 32 lanes per node, 8 nodes per block. Transposed weights in LDS.
__global__ __launch_bounds__(256) void gru_kernel(
    float* __restrict__ x, const float* __restrict__ m,
    const float* __restrict__ W_ih, const float* __restrict__ W_hh,
    const float* __restrict__ b_ih, const float* __restrict__ b_hh) {
  __shared__ float wih[64 * 96];  // wih[k*96+q] = W_ih[q][k]
  __shared__ float whh[32 * 96];  // whh[k*96+q] = W_hh[q][k]
  __shared__ float xs[8][32], ms[8][32];
  int t = threadIdx.x;
  for (int p = t; p < 96 * 64; p += 256) {
    int q = p >> 6, k = p & 63;
    wih[k * 96 + q] = W_ih[p];
  }
  for (int p = t; p < 96 * 32; p += 256) {
    int q = p >> 5, k = p & 31;
    whh[k * 96 + q] = W_hh[p];
  }
  int slot = t >> 5, i = t & 31;
  int n = blockIdx.x * 8 + slot;
  xs[slot][i] = x[(size_t)n * H + i];
  ms[slot][i] = m[(size_t)n * H + i];
  __syncthreads();

  float gir = b_ih[i], giz = b_ih[32 + i], gin = b_ih[64 + i];
  float ghr = b_hh[i], ghz = b_hh[32 + i], ghn = b_hh[64 + i];
#pragma unroll 4
  for (int k = 0; k < 32; k++) {
    float xk = xs[slot][k];
    float mk = ms[slot][k];
    const float* wa = &wih[k * 96];
    const float* wb = &wih[(32 + k) * 96];
    gir += xk * wa[i] + mk * wb[i];
    giz += xk * wa[32 + i] + mk * wb[32 + i];
    gin += xk * wa[64 + i] + mk * wb[64 + i];
    const float* hc = &whh[k * 96];
    ghr += xk * hc[i];
    ghz += xk * hc[32 + i];
    ghn += xk * hc[64 + i];
  }
  float r = 1.f / (1.f + __expf(-(gir + ghr)));
  float z = 1.f / (1.f + __expf(-(giz + ghz)));
  float nn = tanhf(gin + r * ghn);
  x[(size_t)n * H + i] = (1.f - z) * nn + z * xs[slot][i];
}

// float4 copy / zero (avoid hipMemcpyAsync/hipMemsetAsync during capture)
__global__ void copy4_kernel(float4* __restrict__ dst, const float4* __restrict__ src, int n4) {
  int i = blockIdx.x * blockDim.x + threadIdx.x;
  if (i < n4) dst[i] = src[i];
}
__global__ void zero4_kernel(float4* __restrict__ dst, int n4) {
  int i = blockIdx.x * blockDim.x + threadIdx.x;
  if (i < n4) dst[i] = make_float4(0.f, 0.f, 0.f, 0.f);
}

extern "C" void kernel_launch(void* const* d_in, const int* in_sizes, int n_in,
                              void* d_out, int out_size, void* d_ws, size_t ws_size,
                              hipStream_t stream) {
  const float* x_in      = (const float*)d_in[0];
  const float* edge_data = (const float*)d_in[1];
  const int*   edges     = (const int*)d_in[2];
  // d_in[3] = T (always 8; hard-coded)
  const float* W1   = (const float*)d_in[4];
  const float* b1   = (const float*)d_in[5];
  const float* W2   = (const float*)d_in[6];
  const float* b2   = (const float*)d_in[7];
  const float* W_ih = (const float*)d_in[8];
  const float* W_hh = (const float*)d_in[9];
  const float* b_ih = (const float*)d_in[10];
  const float* b_hh = (const float*)d_in[11];

  // Workspace: hidh 25.6MB | hidl 25.6MB | W2Fh 128KB | W2Fl 128KB | m 6.4MB (~58MB)
  char* ws = (char*)d_ws;
  size_t off = 0;
  uint32_t* hidh = (uint32_t*)(ws + off); off += (size_t)N_EDGES * 64 * 2;
  uint32_t* hidl = (uint32_t*)(ws + off); off += (size_t)N_EDGES * 64 * 2;
  uint32_t* W2Fh = (uint32_t*)(ws + off); off += 32768u * 4;
  uint32_t* W2Fl = (uint32_t*)(ws + off); off += 32768u * 4;
  float*    m    = (float*)(ws + off);
  float*    x    = (float*)d_out;   // iterate x in-place in d_out

  const int n4x = N_NODES * H / 4;  // 400000
  copy4_kernel<<<(n4x + 255) / 256, 256, 0, stream>>>((float4*)x, (const float4*)x_in, n4x);

  hidb_kernel<<<N_EDGES * 32 / 256, 256, 0, stream>>>(edge_data, W1, b1, hidh, hidl);
  w2pack_kernel<<<32768 / 256, 256, 0, stream>>>(W2, W2Fh, W2Fl);

  for (int it = 0; it < T_STEPS; it++) {
    zero4_kernel<<<(n4x + 255) / 256, 256, 0, stream>>>((float4*)m, n4x);
    msg_kernel<<<1024, 256, 0, stream>>>(W2Fh, W2Fl, hidh, hidl, b2, x, edges, m);
    gru_kernel<<<N_NODES / 8, 256, 0, stream>>>(x, m, W_ih, W_hh, b_ih, b_hh);
  }
}

// Round 9
// 4032.796 us; speedup vs baseline: 1.6858x; 1.6858x over previous
//
#include <hip/hip_runtime.h>
#include <stdint.h>

#define N_NODES 50000
#define N_EDGES 200000
#define H 32
#define T_STEPS 8
#define NGROUPS (N_EDGES / 64)   // 3125

typedef __attribute__((ext_vector_type(4))) float v4f;
typedef __attribute__((ext_vector_type(8))) _Float16 h8;

#define LO_SCALE 4096.0f
#define LO_DESCALE 2.44140625e-4f  // 1/4096

__device__ __forceinline__ uint32_t packh2(_Float16 a, _Float16 b) {
  return (uint32_t)__builtin_bit_cast(unsigned short, a) |
         ((uint32_t)__builtin_bit_cast(unsigned short, b) << 16);
}

// hid[e][d] = relu(edge_data[e].W1[d] + b1[d]), fp16 hi + scaled-lo. (R4 verbatim)
__global__ void hidb_kernel(const float* __restrict__ ed, const float* __restrict__ W1,
                            const float* __restrict__ b1,
                            uint32_t* __restrict__ hidh, uint32_t* __restrict__ hidl) {
  int idx = blockIdx.x * blockDim.x + threadIdx.x;   // E*32 threads
  int e = idx >> 5, d2 = idx & 31;
  int d0 = d2 * 2;
  const float4* er = (const float4*)(ed + (size_t)e * 16);
  const float4* w0 = (const float4*)(W1 + (size_t)d0 * 16);
  const float4* w1 = (const float4*)(W1 + (size_t)(d0 + 1) * 16);
  float a0 = b1[d0], a1 = b1[d0 + 1];
#pragma unroll
  for (int k = 0; k < 4; k++) {
    float4 h = er[k], u = w0[k], v = w1[k];
    a0 += h.x * u.x + h.y * u.y + h.z * u.z + h.w * u.w;
    a1 += h.x * v.x + h.y * v.y + h.z * v.z + h.w * v.w;
  }
  a0 = fmaxf(a0, 0.f);
  a1 = fmaxf(a1, 0.f);
  _Float16 h0 = (_Float16)a0, h1 = (_Float16)a1;
  _Float16 l0 = (_Float16)((a0 - (float)h0) * LO_SCALE);
  _Float16 l1 = (_Float16)((a1 - (float)h1) * LO_SCALE);
  hidh[idx] = packh2(h0, h1);
  hidl[idx] = packh2(l0, l1);
}

// Pack W2 into MFMA A-fragment-linear fp16 hi / scaled-lo. (R4 verbatim)
__global__ void w2pack_kernel(const float* __restrict__ W2,
                              uint32_t* __restrict__ W2Fh, uint32_t* __restrict__ W2Fl) {
  int o = blockIdx.x * blockDim.x + threadIdx.x;   // 32768 threads
  int c = o >> 8, u = o & 255;
  int lane = u >> 2, pr = u & 3;
  int mtg = c >> 1, kh = c & 1;
  int row = mtg * 16 + (lane & 15);
  int k = kh * 32 + (lane >> 4) * 8 + pr * 2;
  float v0 = W2[(size_t)row * 64 + k];
  float v1 = W2[(size_t)row * 64 + k + 1];
  _Float16 h0 = (_Float16)v0, h1 = (_Float16)v1;
  _Float16 l0 = (_Float16)((v0 - (float)h0) * LO_SCALE);
  _Float16 l1 = (_Float16)((v1 - (float)h1) * LO_SCALE);
  W2Fh[o] = packh2(h0, h1);
  W2Fl[o] = packh2(l0, l1);
}

// Message build: Round-4 msg_kernel VERBATIM (mq quarters, hi+lo both in LDS,
// identical MFMA sequence) except the epilogue: instead of atomicAdd into m,
// store the 8-float quarter-row into the chunked msg buffer (plain stores,
// single-writer per (e, i-quarter)).
__global__ __launch_bounds__(256, 2) void msg_kernel(
    const uint32_t* __restrict__ W2Fh, const uint32_t* __restrict__ W2Fl,
    const uint32_t* __restrict__ hidh, const uint32_t* __restrict__ hidl,
    const float* __restrict__ b2, const float* __restrict__ x,
    const int* __restrict__ edges, float* __restrict__ msg,
    int g0, int gcount) {
  __shared__ uint32_t w2h[8192];   // 32 KB: this block's M-quarter, hi
  __shared__ uint32_t w2l[8192];   // 32 KB: scaled lo
  __shared__ float b2s[256];
  int t = threadIdx.x;
  int mq = blockIdx.x & 3;
  for (int p = t; p < 8192; p += 256) {
    w2h[p] = W2Fh[mq * 8192 + p];
    w2l[p] = W2Fl[mq * 8192 + p];
  }
  b2s[t] = b2[mq * 256 + t];
  __syncthreads();

  int wv = t >> 6, lane = t & 63;
  int el = lane & 15, kg = lane >> 4;
  const h8* sh = (const h8*)w2h;
  const h8* sl = (const h8*)w2l;
  const h8* hbh = (const h8*)hidh;
  const h8* hbl = (const h8*)hidl;

  for (int g = (int)(blockIdx.x >> 2); g < gcount; g += 256) {
    int es = g0 + g;
    int e = es * 64 + wv * 16 + el;        // global edge
    int eloc = g * 64 + wv * 16 + el;      // chunk-local msg row
    int src = edges[2 * e];
    h8 bh0 = hbh[(size_t)e * 8 + kg];
    h8 bh1 = hbh[(size_t)e * 8 + 4 + kg];
    h8 bl0 = hbl[(size_t)e * 8 + kg];
    h8 bl1 = hbl[(size_t)e * 8 + 4 + kg];
    v4f xr0 = *(const v4f*)(x + (size_t)src * 32 + kg * 4);
    v4f xr1 = *(const v4f*)(x + (size_t)src * 32 + 16 + kg * 4);

    float sacc[8];
#pragma unroll
    for (int mp = 0; mp < 8; mp++) {
      float tacc = 0.f;
#pragma unroll
      for (int tp = 0; tp < 2; tp++) {
        int mt = 2 * mp + tp;
        h8 ah0 = sh[(size_t)(mt * 2 + 0) * 64 + lane];
        h8 ah1 = sh[(size_t)(mt * 2 + 1) * 64 + lane];
        h8 al0 = sl[(size_t)(mt * 2 + 0) * 64 + lane];
        h8 al1 = sl[(size_t)(mt * 2 + 1) * 64 + lane];
        v4f chi = *(const v4f*)(b2s + mt * 16 + kg * 4);   // bias as C-init
        chi = __builtin_amdgcn_mfma_f32_16x16x32_f16(ah0, bh0, chi, 0, 0, 0);
        chi = __builtin_amdgcn_mfma_f32_16x16x32_f16(ah1, bh1, chi, 0, 0, 0);
        v4f clo = {0.f, 0.f, 0.f, 0.f};
        clo = __builtin_amdgcn_mfma_f32_16x16x32_f16(ah0, bl0, clo, 0, 0, 0);
        clo = __builtin_amdgcn_mfma_f32_16x16x32_f16(ah1, bl1, clo, 0, 0, 0);
        clo = __builtin_amdgcn_mfma_f32_16x16x32_f16(al0, bh0, clo, 0, 0, 0);
        clo = __builtin_amdgcn_mfma_f32_16x16x32_f16(al1, bh1, clo, 0, 0, 0);
        v4f xr = tp ? xr1 : xr0;
#pragma unroll
        for (int r = 0; r < 4; r++) {
          float av = fmaxf(fmaf(clo[r], LO_DESCALE, chi[r]), 0.f);
          tacc = fmaf(av, xr[r], tacc);
        }
      }
      float s = tacc;
      s += __shfl_xor(s, 16, 64);
      s += __shfl_xor(s, 32, 64);
      sacc[mp] = s;   // msg[e][mq*8+mp]
    }
    if (lane < 16) {
      float* mrow = msg + (size_t)eloc * 32 + mq * 8;
      v4f s0 = {sacc[0], sacc[1], sacc[2], sacc[3]};
      v4f s1 = {sacc[4], sacc[5], sacc[6], sacc[7]};
      *(v4f*)(mrow + 0) = s0;
      *(v4f*)(mrow + 4) = s1;
    }
  }
}

// Aggregation: atomic scatter from msg chunk into m (R4 aggregation semantics).
__global__ void scatmsg_kernel(const float* __restrict__ msg, const int* __restrict__ edges,
                               float* __restrict__ m, int e0, int ecount) {
  int idx = blockIdx.x * blockDim.x + threadIdx.x;
  if (idx >= ecount * 32) return;
  int i = idx & 31;
  int el = idx >> 5;
  int e = e0 + el;
  float v = msg[(size_t)el * 32 + i];
  int s = edges[2 * e], d = edges[2 * e + 1];
  atomicAdd(&m[(size_t)s * 32 + i], v);
  if (d != s) atomicAdd(&m[(size_t)d * 32 + i], v);
}

// GRU (R4 verbatim, proven).
__global__ __launch_bounds__(256) void gru_kernel(
    float* __restrict__ x, const float* __restrict__ m,
    const float* __restrict__ W_ih, const float* __restrict__ W_hh,
    const float* __restrict__ b_ih, const float* __restrict__ b_hh) {
  __shared__ float wih[64 * 96];
  __shared__ float whh[32 * 96];
  __shared__ float xs[8][32], ms[8][32];
  int t = threadIdx.x;
  for (int p = t; p < 96 * 64; p += 256) {
    int q = p >> 6, k = p & 63;
    wih[k * 96 + q] = W_ih[p];
  }
  for (int p = t; p < 96 * 32; p += 256) {
    int q = p >> 5, k = p & 31;
    whh[k * 96 + q] = W_hh[p];
  }
  int slot = t >> 5, i = t & 31;
  int n = blockIdx.x * 8 + slot;
  xs[slot][i] = x[(size_t)n * H + i];
  ms[slot][i] = m[(size_t)n * H + i];
  __syncthreads();

  float gir = b_ih[i], giz = b_ih[32 + i], gin = b_ih[64 + i];
  float ghr = b_hh[i], ghz = b_hh[32 + i], ghn = b_hh[64 + i];
#pragma unroll 4
  for (int k = 0; k < 32; k++) {
    float xk = xs[slot][k];
    float mk = ms[slot][k];
    const float* wa = &wih[k * 96];
    const float* wb = &wih[(32 + k) * 96];
    gir += xk * wa[i] + mk * wb[i];
    giz += xk * wa[32 + i] + mk * wb[32 + i];
    gin += xk * wa[64 + i] + mk * wb[64 + i];
    const float* hc = &whh[k * 96];
    ghr += xk * hc[i];
    ghz += xk * hc[32 + i];
    ghn += xk * hc[64 + i];
  }
  float r = 1.f / (1.f + __expf(-(gir + ghr)));
  float z = 1.f / (1.f + __expf(-(giz + ghz)));
  float nn = tanhf(gin + r * ghn);
  x[(size_t)n * H + i] = (1.f - z) * nn + z * xs[slot][i];
}

__global__ void copy4_kernel(float4* __restrict__ dst, const float4* __restrict__ src, int n4) {
  int i = blockIdx.x * blockDim.x + threadIdx.x;
  if (i < n4) dst[i] = src[i];
}
__global__ void zero4_kernel(float4* __restrict__ dst, int n4) {
  int i = blockIdx.x * blockDim.x + threadIdx.x;
  if (i < n4) dst[i] = make_float4(0.f, 0.f, 0.f, 0.f);
}

extern "C" void kernel_launch(void* const* d_in, const int* in_sizes, int n_in,
                              void* d_out, int out_size, void* d_ws, size_t ws_size,
                              hipStream_t stream) {
  const float* x_in      = (const float*)d_in[0];
  const float* edge_data = (const float*)d_in[1];
  const int*   edges     = (const int*)d_in[2];
  // d_in[3] = T (always 8; hard-coded)
  const float* W1   = (const float*)d_in[4];
  const float* b1   = (const float*)d_in[5];
  const float* W2   = (const float*)d_in[6];
  const float* b2   = (const float*)d_in[7];
  const float* W_ih = (const float*)d_in[8];
  const float* W_hh = (const float*)d_in[9];
  const float* b_ih = (const float*)d_in[10];
  const float* b_hh = (const float*)d_in[11];

  // Base layout = R4's proven 57.86 MB: hidh | hidl | W2Fh | W2Fl | m.
  // msg chunk buffer sized adaptively from ws_size (never exceeds ws_size).
  char* ws = (char*)d_ws;
  size_t o = 0;
  uint32_t* hidh = (uint32_t*)(ws + o); o += (size_t)N_EDGES * 64 * 2;   // 25.6 MB
  uint32_t* hidl = (uint32_t*)(ws + o); o += (size_t)N_EDGES * 64 * 2;   // 25.6 MB
  uint32_t* W2Fh = (uint32_t*)(ws + o); o += 32768u * 4;
  uint32_t* W2Fl = (uint32_t*)(ws + o); o += 32768u * 4;
  float*    m    = (float*)(ws + o);    o += (size_t)N_NODES * 32 * 4;   // 6.4 MB
  float*    msg  = (float*)(ws + o);    // variable-size chunk buffer
  float*    x    = (float*)d_out;

  // Each 64-edge group needs 8192 B of msg space.
  size_t avail = (ws_size > o) ? (ws_size - o) : 0;
  long long mg = (long long)(avail / 8192);
  int maxGroups = (mg < 16) ? 16 : (mg > NGROUPS ? NGROUPS : (int)mg);
  int nChunks = (NGROUPS + maxGroups - 1) / maxGroups;
  int cgroups = (NGROUPS + nChunks - 1) / nChunks;

  const int n4x = N_NODES * H / 4;  // 400000
  copy4_kernel<<<(n4x + 255) / 256, 256, 0, stream>>>((float4*)x, (const float4*)x_in, n4x);
  hidb_kernel<<<N_EDGES * 32 / 256, 256, 0, stream>>>(edge_data, W1, b1, hidh, hidl);
  w2pack_kernel<<<32768 / 256, 256, 0, stream>>>(W2, W2Fh, W2Fl);

  for (int it = 0; it < T_STEPS; it++) {
    zero4_kernel<<<(n4x + 255) / 256, 256, 0, stream>>>((float4*)m, n4x);
    for (int c = 0; c < nChunks; c++) {
      int g0 = c * cgroups;
      int gc = NGROUPS - g0; if (gc > cgroups) gc = cgroups;
      if (gc <= 0) break;
      msg_kernel<<<1024, 256, 0, stream>>>(W2Fh, W2Fl, hidh, hidl, b2, x, edges,
                                           msg, g0, gc);
      scatmsg_kernel<<<gc * 8, 256, 0, stream>>>(msg, edges, m, g0 * 64, gc * 64);
    }
    gru_kernel<<<N_NODES / 8, 256, 0, stream>>>(x, m, W_ih, W_hh, b_ih, b_hh);
  }
}

// Round 11
// 3452.786 us; speedup vs baseline: 1.9690x; 1.1680x over previous
//
#include <hip/hip_runtime.h>
#include <stdint.h>

#define N_NODES 50000
#define N_EDGES 200000
#define H 32
#define T_STEPS 8
#define NGROUPS (N_EDGES / 64)   // 3125

typedef __attribute__((ext_vector_type(4))) float v4f;
typedef __attribute__((ext_vector_type(8))) _Float16 h8;

#define LO_SCALE 4096.0f
#define LO_DESCALE 2.44140625e-4f  // 1/4096

__device__ __forceinline__ uint32_t packh2(_Float16 a, _Float16 b) {
  return (uint32_t)__builtin_bit_cast(unsigned short, a) |
         ((uint32_t)__builtin_bit_cast(unsigned short, b) << 16);
}

// hid[e][d] = relu(edge_data[e].W1[d] + b1[d]), fp16 hi + scaled-lo. (proven)
__global__ void hidb_kernel(const float* __restrict__ ed, const float* __restrict__ W1,
                            const float* __restrict__ b1,
                            uint32_t* __restrict__ hidh, uint32_t* __restrict__ hidl) {
  int idx = blockIdx.x * blockDim.x + threadIdx.x;   // E*32 threads
  int e = idx >> 5, d2 = idx & 31;
  int d0 = d2 * 2;
  const float4* er = (const float4*)(ed + (size_t)e * 16);
  const float4* w0 = (const float4*)(W1 + (size_t)d0 * 16);
  const float4* w1 = (const float4*)(W1 + (size_t)(d0 + 1) * 16);
  float a0 = b1[d0], a1 = b1[d0 + 1];
#pragma unroll
  for (int k = 0; k < 4; k++) {
    float4 h = er[k], u = w0[k], v = w1[k];
    a0 += h.x * u.x + h.y * u.y + h.z * u.z + h.w * u.w;
    a1 += h.x * v.x + h.y * v.y + h.z * v.z + h.w * v.w;
  }
  a0 = fmaxf(a0, 0.f);
  a1 = fmaxf(a1, 0.f);
  _Float16 h0 = (_Float16)a0, h1 = (_Float16)a1;
  _Float16 l0 = (_Float16)((a0 - (float)h0) * LO_SCALE);
  _Float16 l1 = (_Float16)((a1 - (float)h1) * LO_SCALE);
  hidh[idx] = packh2(h0, h1);
  hidl[idx] = packh2(l0, l1);
}

// Pack W2 into MFMA A-fragment-linear fp16 hi / scaled-lo. (proven)
__global__ void w2pack_kernel(const float* __restrict__ W2,
                              uint32_t* __restrict__ W2Fh, uint32_t* __restrict__ W2Fl) {
  int o = blockIdx.x * blockDim.x + threadIdx.x;   // 32768 threads
  int c = o >> 8, u = o & 255;
  int lane = u >> 2, pr = u & 3;
  int mtg = c >> 1, kh = c & 1;
  int row = mtg * 16 + (lane & 15);
  int k = kh * 32 + (lane >> 4) * 8 + pr * 2;
  float v0 = W2[(size_t)row * 64 + k];
  float v1 = W2[(size_t)row * 64 + k + 1];
  _Float16 h0 = (_Float16)v0, h1 = (_Float16)v1;
  _Float16 l0 = (_Float16)((v0 - (float)h0) * LO_SCALE);
  _Float16 l1 = (_Float16)((v1 - (float)h1) * LO_SCALE);
  W2Fh[o] = packh2(h0, h1);
  W2Fl[o] = packh2(l0, l1);
}

// ---------- CSR incidence build (now on the output path) ----------
__global__ void zero_cur_kernel(int* __restrict__ cur) {
  int i = blockIdx.x * blockDim.x + threadIdx.x;
  if (i < N_NODES) cur[i] = 0;
}
__global__ void count_kernel(const int* __restrict__ edges, int* __restrict__ cur) {
  int e = blockIdx.x * blockDim.x + threadIdx.x;
  if (e < N_EDGES) {
    int s = edges[2 * e], d = edges[2 * e + 1];
    atomicAdd(&cur[s], 1);
    if (d != s) atomicAdd(&cur[d], 1);
  }
}
__global__ __launch_bounds__(1024) void scan_kernel(int* __restrict__ cur,
                                                    int* __restrict__ off) {
  __shared__ int lds[1024];
  int t = threadIdx.x;
  int base = t * 49;
  int cnt = 0;
  for (int j = 0; j < 49; j++) {
    int idx = base + j;
    if (idx < N_NODES) cnt += cur[idx];
  }
  lds[t] = cnt;
  __syncthreads();
  for (int d = 1; d < 1024; d <<= 1) {
    int v = (t >= d) ? lds[t - d] : 0;
    __syncthreads();
    lds[t] += v;
    __syncthreads();
  }
  int run = lds[t] - cnt;   // exclusive prefix of this thread's chunk
  for (int j = 0; j < 49; j++) {
    int idx = base + j;
    if (idx < N_NODES) {
      int c = cur[idx];
      off[idx] = run;
      cur[idx] = run;
      run += c;
    }
  }
  if (t == 1023) off[N_NODES] = lds[1023];
}
__global__ void scatter_kernel(const int* __restrict__ edges, int* __restrict__ cur,
                               int* __restrict__ inc) {
  int e = blockIdx.x * blockDim.x + threadIdx.x;
  if (e < N_EDGES) {
    int s = edges[2 * e], d = edges[2 * e + 1];
    int p = atomicAdd(&cur[s], 1);
    inc[p] = e;
    if (d != s) {
      p = atomicAdd(&cur[d], 1);
      inc[p] = e;
    }
  }
}

// ---------- message build: R9 msg_kernel VERBATIM (quarters, hi+lo in LDS) ----------
__global__ __launch_bounds__(256, 2) void msg_kernel(
    const uint32_t* __restrict__ W2Fh, const uint32_t* __restrict__ W2Fl,
    const uint32_t* __restrict__ hidh, const uint32_t* __restrict__ hidl,
    const float* __restrict__ b2, const float* __restrict__ x,
    const int* __restrict__ edges, float* __restrict__ msg,
    int g0, int gcount) {
  __shared__ uint32_t w2h[8192];   // 32 KB: this block's M-quarter, hi
  __shared__ uint32_t w2l[8192];   // 32 KB: scaled lo
  __shared__ float b2s[256];
  int t = threadIdx.x;
  int mq = blockIdx.x & 3;
  for (int p = t; p < 8192; p += 256) {
    w2h[p] = W2Fh[mq * 8192 + p];
    w2l[p] = W2Fl[mq * 8192 + p];
  }
  b2s[t] = b2[mq * 256 + t];
  __syncthreads();

  int wv = t >> 6, lane = t & 63;
  int el = lane & 15, kg = lane >> 4;
  const h8* sh = (const h8*)w2h;
  const h8* sl = (const h8*)w2l;
  const h8* hbh = (const h8*)hidh;
  const h8* hbl = (const h8*)hidl;

  for (int g = (int)(blockIdx.x >> 2); g < gcount; g += 256) {
    int es = g0 + g;
    int e = es * 64 + wv * 16 + el;        // global edge
    int eloc = g * 64 + wv * 16 + el;      // chunk-local msg row
    int src = edges[2 * e];
    h8 bh0 = hbh[(size_t)e * 8 + kg];
    h8 bh1 = hbh[(size_t)e * 8 + 4 + kg];
    h8 bl0 = hbl[(size_t)e * 8 + kg];
    h8 bl1 = hbl[(size_t)e * 8 + 4 + kg];
    v4f xr0 = *(const v4f*)(x + (size_t)src * 32 + kg * 4);
    v4f xr1 = *(const v4f*)(x + (size_t)src * 32 + 16 + kg * 4);

    float sacc[8];
#pragma unroll
    for (int mp = 0; mp < 8; mp++) {
      float tacc = 0.f;
#pragma unroll
      for (int tp = 0; tp < 2; tp++) {
        int mt = 2 * mp + tp;
        h8 ah0 = sh[(size_t)(mt * 2 + 0) * 64 + lane];
        h8 ah1 = sh[(size_t)(mt * 2 + 1) * 64 + lane];
        h8 al0 = sl[(size_t)(mt * 2 + 0) * 64 + lane];
        h8 al1 = sl[(size_t)(mt * 2 + 1) * 64 + lane];
        v4f chi = *(const v4f*)(b2s + mt * 16 + kg * 4);   // bias as C-init
        chi = __builtin_amdgcn_mfma_f32_16x16x32_f16(ah0, bh0, chi, 0, 0, 0);
        chi = __builtin_amdgcn_mfma_f32_16x16x32_f16(ah1, bh1, chi, 0, 0, 0);
        v4f clo = {0.f, 0.f, 0.f, 0.f};
        clo = __builtin_amdgcn_mfma_f32_16x16x32_f16(ah0, bl0, clo, 0, 0, 0);
        clo = __builtin_amdgcn_mfma_f32_16x16x32_f16(ah1, bl1, clo, 0, 0, 0);
        clo = __builtin_amdgcn_mfma_f32_16x16x32_f16(al0, bh0, clo, 0, 0, 0);
        clo = __builtin_amdgcn_mfma_f32_16x16x32_f16(al1, bh1, clo, 0, 0, 0);
        v4f xr = tp ? xr1 : xr0;
#pragma unroll
        for (int r = 0; r < 4; r++) {
          float av = fmaxf(fmaf(clo[r], LO_DESCALE, chi[r]), 0.f);
          tacc = fmaf(av, xr[r], tacc);
        }
      }
      float s = tacc;
      s += __shfl_xor(s, 16, 64);
      s += __shfl_xor(s, 32, 64);
      sacc[mp] = s;   // msg[e][mq*8+mp]
    }
    if (lane < 16) {
      float* mrow = msg + (size_t)eloc * 32 + mq * 8;
      v4f s0 = {sacc[0], sacc[1], sacc[2], sacc[3]};
      v4f s1 = {sacc[4], sacc[5], sacc[6], sacc[7]};
      *(v4f*)(mrow + 0) = s0;
      *(v4f*)(mrow + 4) = s1;
    }
  }
}

// ---------- per-iteration: CSR gather + GRU, fused (replaces zero4+scatmsg+gru)
// 512 threads = 16 nodes x 32 lanes. Weights transposed in LDS, stride 97.
__global__ __launch_bounds__(512) void node_kernel(
    float* __restrict__ x, const float* __restrict__ msg,
    const int* __restrict__ off, const int* __restrict__ inc,
    const float* __restrict__ W_ih, const float* __restrict__ W_hh,
    const float* __restrict__ b_ih, const float* __restrict__ b_hh) {
  __shared__ float wih[64 * 97];   // wih[k*97+q] = W_ih[q][k]
  __shared__ float whh[32 * 97];
  __shared__ float xs[16][32], ms[16][32];
  int t = threadIdx.x;
  for (int p = t; p < 6144; p += 512) {
    int q = p >> 6, k = p & 63;
    wih[k * 97 + q] = W_ih[p];
  }
  for (int p = t; p < 3072; p += 512) {
    int q = p >> 5, k = p & 31;
    whh[k * 97 + q] = W_hh[p];
  }
  int slot = t >> 5, i = t & 31;
  int n = blockIdx.x * 16 + slot;   // 3125*16 = 50000 exact
  float xv = x[(size_t)n * 32 + i];
  xs[slot][i] = xv;
  float acc = 0.f;
  int s0 = off[n], s1 = off[n + 1];
  for (int k = s0; k < s1; k++) {
    int e = inc[k];
    acc += msg[(size_t)e * 32 + i];
  }
  ms[slot][i] = acc;
  __syncthreads();

  float gir = b_ih[i], giz = b_ih[32 + i], gin = b_ih[64 + i];
  float ghr = b_hh[i], ghz = b_hh[32 + i], ghn = b_hh[64 + i];
#pragma unroll 4
  for (int k = 0; k < 32; k++) {
    float xk = xs[slot][k];
    float mk = ms[slot][k];
    const float* wa = &wih[k * 97];          // W_ih[.][k]     (x part)
    const float* wb = &wih[(32 + k) * 97];   // W_ih[.][32+k]  (m part)
    gir += xk * wa[i] + mk * wb[i];
    giz += xk * wa[32 + i] + mk * wb[32 + i];
    gin += xk * wa[64 + i] + mk * wb[64 + i];
    const float* hc = &whh[k * 97];
    ghr += xk * hc[i];
    ghz += xk * hc[32 + i];
    ghn += xk * hc[64 + i];
  }
  float r = 1.f / (1.f + __expf(-(gir + ghr)));
  float z = 1.f / (1.f + __expf(-(giz + ghz)));
  float nn = tanhf(gin + r * ghn);
  x[(size_t)n * 32 + i] = (1.f - z) * nn + z * xv;
}

__global__ void copy4_kernel(float4* __restrict__ dst, const float4* __restrict__ src, int n4) {
  int i = blockIdx.x * blockDim.x + threadIdx.x;
  if (i < n4) dst[i] = src[i];
}

extern "C" void kernel_launch(void* const* d_in, const int* in_sizes, int n_in,
                              void* d_out, int out_size, void* d_ws, size_t ws_size,
                              hipStream_t stream) {
  const float* x_in      = (const float*)d_in[0];
  const float* edge_data = (const float*)d_in[1];
  const int*   edges     = (const int*)d_in[2];
  // d_in[3] = T (always 8; hard-coded)
  const float* W1   = (const float*)d_in[4];
  const float* b1   = (const float*)d_in[5];
  const float* W2   = (const float*)d_in[6];
  const float* b2   = (const float*)d_in[7];
  const float* W_ih = (const float*)d_in[8];
  const float* W_hh = (const float*)d_in[9];
  const float* b_ih = (const float*)d_in[10];
  const float* b_hh = (const float*)d_in[11];

  // Workspace 79.06 MB (< 83.59 MB proven by R9's nChunks==1 dispatch pattern):
  // hidh 25.6M | hidl 25.6M | W2Fh 128K | W2Fl 128K | inc 1.6M | off | cur | msg 25.6M
  char* ws = (char*)d_ws;
  size_t o = 0;
  uint32_t* hidh = (uint32_t*)(ws + o); o += (size_t)N_EDGES * 64 * 2;
  uint32_t* hidl = (uint32_t*)(ws + o); o += (size_t)N_EDGES * 64 * 2;
  uint32_t* W2Fh = (uint32_t*)(ws + o); o += 32768u * 4;
  uint32_t* W2Fl = (uint32_t*)(ws + o); o += 32768u * 4;
  int*      inc  = (int*)(ws + o);      o += (size_t)2 * N_EDGES * 4;
  int*      off  = (int*)(ws + o);      o += (size_t)(N_NODES + 4) * 4;
  int*      cur  = (int*)(ws + o);      o += (size_t)N_NODES * 4;
  float*    msg  = (float*)(ws + o);    o += (size_t)N_EDGES * 32 * 4;
  float*    x    = (float*)d_out;   // iterate x in-place in d_out

  const int n4x = N_NODES * H / 4;  // 400000
  copy4_kernel<<<(n4x + 255) / 256, 256, 0, stream>>>((float4*)x, (const float4*)x_in, n4x);
  hidb_kernel<<<N_EDGES * 32 / 256, 256, 0, stream>>>(edge_data, W1, b1, hidh, hidl);
  w2pack_kernel<<<32768 / 256, 256, 0, stream>>>(W2, W2Fh, W2Fl);

  zero_cur_kernel<<<(N_NODES + 255) / 256, 256, 0, stream>>>(cur);
  count_kernel<<<(N_EDGES + 255) / 256, 256, 0, stream>>>(edges, cur);
  scan_kernel<<<1, 1024, 0, stream>>>(cur, off);
  scatter_kernel<<<(N_EDGES + 255) / 256, 256, 0, stream>>>(edges, cur, inc);

  for (int it = 0; it < T_STEPS; it++) {
    msg_kernel<<<1024, 256, 0, stream>>>(W2Fh, W2Fl, hidh, hidl, b2, x, edges,
                                         msg, 0, NGROUPS);
    node_kernel<<<N_NODES / 16, 512, 0, stream>>>(x, msg, off, inc,
                                                  W_ih, W_hh, b_ih, b_hh);
  }
}

// Round 12
// 3229.403 us; speedup vs baseline: 2.1052x; 1.0692x over previous
//
#include <hip/hip_runtime.h>
#include <stdint.h>

#define N_NODES 50000
#define N_EDGES 200000
#define H 32
#define T_STEPS 8
#define NGROUPS (N_EDGES / 64)   // 3125

typedef __attribute__((ext_vector_type(4))) float v4f;
typedef __attribute__((ext_vector_type(8))) _Float16 h8;

#define LO_SCALE 4096.0f
#define LO_DESCALE 2.44140625e-4f  // 1/4096

__device__ __forceinline__ uint32_t packh2(_Float16 a, _Float16 b) {
  return (uint32_t)__builtin_bit_cast(unsigned short, a) |
         ((uint32_t)__builtin_bit_cast(unsigned short, b) << 16);
}

// hid[e][d] = relu(edge_data[e].W1[d] + b1[d]), fp16 hi + scaled-lo. (proven)
__global__ void hidb_kernel(const float* __restrict__ ed, const float* __restrict__ W1,
                            const float* __restrict__ b1,
                            uint32_t* __restrict__ hidh, uint32_t* __restrict__ hidl) {
  int idx = blockIdx.x * blockDim.x + threadIdx.x;   // E*32 threads
  int e = idx >> 5, d2 = idx & 31;
  int d0 = d2 * 2;
  const float4* er = (const float4*)(ed + (size_t)e * 16);
  const float4* w0 = (const float4*)(W1 + (size_t)d0 * 16);
  const float4* w1 = (const float4*)(W1 + (size_t)(d0 + 1) * 16);
  float a0 = b1[d0], a1 = b1[d0 + 1];
#pragma unroll
  for (int k = 0; k < 4; k++) {
    float4 h = er[k], u = w0[k], v = w1[k];
    a0 += h.x * u.x + h.y * u.y + h.z * u.z + h.w * u.w;
    a1 += h.x * v.x + h.y * v.y + h.z * v.z + h.w * v.w;
  }
  a0 = fmaxf(a0, 0.f);
  a1 = fmaxf(a1, 0.f);
  _Float16 h0 = (_Float16)a0, h1 = (_Float16)a1;
  _Float16 l0 = (_Float16)((a0 - (float)h0) * LO_SCALE);
  _Float16 l1 = (_Float16)((a1 - (float)h1) * LO_SCALE);
  hidh[idx] = packh2(h0, h1);
  hidl[idx] = packh2(l0, l1);
}

// Pack W2 into MFMA A-fragment-linear fp16 hi / scaled-lo. (proven)
__global__ void w2pack_kernel(const float* __restrict__ W2,
                              uint32_t* __restrict__ W2Fh, uint32_t* __restrict__ W2Fl) {
  int o = blockIdx.x * blockDim.x + threadIdx.x;   // 32768 threads
  int c = o >> 8, u = o & 255;
  int lane = u >> 2, pr = u & 3;
  int mtg = c >> 1, kh = c & 1;
  int row = mtg * 16 + (lane & 15);
  int k = kh * 32 + (lane >> 4) * 8 + pr * 2;
  float v0 = W2[(size_t)row * 64 + k];
  float v1 = W2[(size_t)row * 64 + k + 1];
  _Float16 h0 = (_Float16)v0, h1 = (_Float16)v1;
  _Float16 l0 = (_Float16)((v0 - (float)h0) * LO_SCALE);
  _Float16 l1 = (_Float16)((v1 - (float)h1) * LO_SCALE);
  W2Fh[o] = packh2(h0, h1);
  W2Fl[o] = packh2(l0, l1);
}

// ---------- CSR incidence build (proven R11) ----------
__global__ void zero_cur_kernel(int* __restrict__ cur) {
  int i = blockIdx.x * blockDim.x + threadIdx.x;
  if (i < N_NODES) cur[i] = 0;
}
__global__ void count_kernel(const int* __restrict__ edges, int* __restrict__ cur) {
  int e = blockIdx.x * blockDim.x + threadIdx.x;
  if (e < N_EDGES) {
    int s = edges[2 * e], d = edges[2 * e + 1];
    atomicAdd(&cur[s], 1);
    if (d != s) atomicAdd(&cur[d], 1);
  }
}
__global__ __launch_bounds__(1024) void scan_kernel(int* __restrict__ cur,
                                                    int* __restrict__ off) {
  __shared__ int lds[1024];
  int t = threadIdx.x;
  int base = t * 49;
  int cnt = 0;
  for (int j = 0; j < 49; j++) {
    int idx = base + j;
    if (idx < N_NODES) cnt += cur[idx];
  }
  lds[t] = cnt;
  __syncthreads();
  for (int d = 1; d < 1024; d <<= 1) {
    int v = (t >= d) ? lds[t - d] : 0;
    __syncthreads();
    lds[t] += v;
    __syncthreads();
  }
  int run = lds[t] - cnt;   // exclusive prefix of this thread's chunk
  for (int j = 0; j < 49; j++) {
    int idx = base + j;
    if (idx < N_NODES) {
      int c = cur[idx];
      off[idx] = run;
      cur[idx] = run;
      run += c;
    }
  }
  if (t == 1023) off[N_NODES] = lds[1023];
}
__global__ void scatter_kernel(const int* __restrict__ edges, int* __restrict__ cur,
                               int* __restrict__ inc) {
  int e = blockIdx.x * blockDim.x + threadIdx.x;
  if (e < N_EDGES) {
    int s = edges[2 * e], d = edges[2 * e + 1];
    int p = atomicAdd(&cur[s], 1);
    inc[p] = e;
    if (d != s) {
      p = atomicAdd(&cur[d], 1);
      inc[p] = e;
    }
  }
}

// ---------- message build: R9/R11 math verbatim; NEW block->work mapping ----------
// blockIdx bits: [2:0]=xcd-lane, [4:3]=mq quarter, [9:5]=stream. The 4 mq
// blocks of a stream share blockIdx%8 -> same XCD (round-robin dispatch) ->
// hid/x/edges lines fetched once per XCD L2 instead of 4x. msg stored
// quarter-major: msg[mq][e][8] -> each wave stores 512 contiguous bytes,
// no cross-XCD line sharing.
__global__ __launch_bounds__(256, 2) void msg_kernel(
    const uint32_t* __restrict__ W2Fh, const uint32_t* __restrict__ W2Fl,
    const uint32_t* __restrict__ hidh, const uint32_t* __restrict__ hidl,
    const float* __restrict__ b2, const float* __restrict__ x,
    const int* __restrict__ edges, float* __restrict__ msg) {
  __shared__ uint32_t w2h[8192];   // 32 KB: this block's M-quarter, hi
  __shared__ uint32_t w2l[8192];   // 32 KB: scaled lo
  __shared__ float b2s[256];
  int t = threadIdx.x;
  int bid = blockIdx.x;
  int xcd = bid & 7;
  int mq = (bid >> 3) & 3;
  int stream = bid >> 5;            // 0..31
  int gstart = xcd + (stream << 3); // 0..255, unique per (xcd,stream)
  for (int p = t; p < 8192; p += 256) {
    w2h[p] = W2Fh[mq * 8192 + p];
    w2l[p] = W2Fl[mq * 8192 + p];
  }
  b2s[t] = b2[mq * 256 + t];
  __syncthreads();

  int wv = t >> 6, lane = t & 63;
  int el = lane & 15, kg = lane >> 4;
  const h8* sh = (const h8*)w2h;
  const h8* sl = (const h8*)w2l;
  const h8* hbh = (const h8*)hidh;
  const h8* hbl = (const h8*)hidl;

  for (int g = gstart; g < NGROUPS; g += 256) {
    int e = g * 64 + wv * 16 + el;
    int src = edges[2 * e];
    h8 bh0 = hbh[(size_t)e * 8 + kg];
    h8 bh1 = hbh[(size_t)e * 8 + 4 + kg];
    h8 bl0 = hbl[(size_t)e * 8 + kg];
    h8 bl1 = hbl[(size_t)e * 8 + 4 + kg];
    v4f xr0 = *(const v4f*)(x + (size_t)src * 32 + kg * 4);
    v4f xr1 = *(const v4f*)(x + (size_t)src * 32 + 16 + kg * 4);

    float sacc[8];
#pragma unroll
    for (int mp = 0; mp < 8; mp++) {
      float tacc = 0.f;
#pragma unroll
      for (int tp = 0; tp < 2; tp++) {
        int mt = 2 * mp + tp;
        h8 ah0 = sh[(size_t)(mt * 2 + 0) * 64 + lane];
        h8 ah1 = sh[(size_t)(mt * 2 + 1) * 64 + lane];
        h8 al0 = sl[(size_t)(mt * 2 + 0) * 64 + lane];
        h8 al1 = sl[(size_t)(mt * 2 + 1) * 64 + lane];
        v4f chi = *(const v4f*)(b2s + mt * 16 + kg * 4);   // bias as C-init
        chi = __builtin_amdgcn_mfma_f32_16x16x32_f16(ah0, bh0, chi, 0, 0, 0);
        chi = __builtin_amdgcn_mfma_f32_16x16x32_f16(ah1, bh1, chi, 0, 0, 0);
        v4f clo = {0.f, 0.f, 0.f, 0.f};
        clo = __builtin_amdgcn_mfma_f32_16x16x32_f16(ah0, bl0, clo, 0, 0, 0);
        clo = __builtin_amdgcn_mfma_f32_16x16x32_f16(ah1, bl1, clo, 0, 0, 0);
        clo = __builtin_amdgcn_mfma_f32_16x16x32_f16(al0, bh0, clo, 0, 0, 0);
        clo = __builtin_amdgcn_mfma_f32_16x16x32_f16(al1, bh1, clo, 0, 0, 0);
        v4f xr = tp ? xr1 : xr0;
#pragma unroll
        for (int r = 0; r < 4; r++) {
          float av = fmaxf(fmaf(clo[r], LO_DESCALE, chi[r]), 0.f);
          tacc = fmaf(av, xr[r], tacc);
        }
      }
      float s = tacc;
      s += __shfl_xor(s, 16, 64);
      s += __shfl_xor(s, 32, 64);
      sacc[mp] = s;   // msg value for (e, i = mq*8+mp)
    }
    if (lane < 16) {
      // quarter-major: msg[mq][e][0..7]; wave's 16 edges -> 512 contiguous B
      float* mrow = msg + ((size_t)mq * N_EDGES + e) * 8;
      v4f s0 = {sacc[0], sacc[1], sacc[2], sacc[3]};
      v4f s1 = {sacc[4], sacc[5], sacc[6], sacc[7]};
      *(v4f*)(mrow + 0) = s0;
      *(v4f*)(mrow + 4) = s1;
    }
  }
}

// ---------- per-iteration: CSR gather + GRU, fused (proven R11; gather
// addressing adapted to quarter-major msg layout) ----------
__global__ __launch_bounds__(512) void node_kernel(
    float* __restrict__ x, const float* __restrict__ msg,
    const int* __restrict__ off, const int* __restrict__ inc,
    const float* __restrict__ W_ih, const float* __restrict__ W_hh,
    const float* __restrict__ b_ih, const float* __restrict__ b_hh) {
  __shared__ float wih[64 * 97];   // wih[k*97+q] = W_ih[q][k]
  __shared__ float whh[32 * 97];
  __shared__ float xs[16][32], ms[16][32];
  int t = threadIdx.x;
  for (int p = t; p < 6144; p += 512) {
    int q = p >> 6, k = p & 63;
    wih[k * 97 + q] = W_ih[p];
  }
  for (int p = t; p < 3072; p += 512) {
    int q = p >> 5, k = p & 31;
    whh[k * 97 + q] = W_hh[p];
  }
  int slot = t >> 5, i = t & 31;
  int n = blockIdx.x * 16 + slot;   // 3125*16 = 50000 exact
  float xv = x[(size_t)n * 32 + i];
  xs[slot][i] = xv;
  float acc = 0.f;
  int s0 = off[n], s1 = off[n + 1];
  const float* msgq = msg + (size_t)(i >> 3) * N_EDGES * 8 + (i & 7);
  for (int k = s0; k < s1; k++) {
    int e = inc[k];
    acc += msgq[(size_t)e * 8];
  }
  ms[slot][i] = acc;
  __syncthreads();

  float gir = b_ih[i], giz = b_ih[32 + i], gin = b_ih[64 + i];
  float ghr = b_hh[i], ghz = b_hh[32 + i], ghn = b_hh[64 + i];
#pragma unroll 4
  for (int k = 0; k < 32; k++) {
    float xk = xs[slot][k];
    float mk = ms[slot][k];
    const float* wa = &wih[k * 97];          // W_ih[.][k]     (x part)
    const float* wb = &wih[(32 + k) * 97];   // W_ih[.][32+k]  (m part)
    gir += xk * wa[i] + mk * wb[i];
    giz += xk * wa[32 + i] + mk * wb[32 + i];
    gin += xk * wa[64 + i] + mk * wb[64 + i];
    const float* hc = &whh[k * 97];
    ghr += xk * hc[i];
    ghz += xk * hc[32 + i];
    ghn += xk * hc[64 + i];
  }
  float r = 1.f / (1.f + __expf(-(gir + ghr)));
  float z = 1.f / (1.f + __expf(-(giz + ghz)));
  float nn = tanhf(gin + r * ghn);
  x[(size_t)n * 32 + i] = (1.f - z) * nn + z * xv;
}

__global__ void copy4_kernel(float4* __restrict__ dst, const float4* __restrict__ src, int n4) {
  int i = blockIdx.x * blockDim.x + threadIdx.x;
  if (i < n4) dst[i] = src[i];
}

extern "C" void kernel_launch(void* const* d_in, const int* in_sizes, int n_in,
                              void* d_out, int out_size, void* d_ws, size_t ws_size,
                              hipStream_t stream) {
  const float* x_in      = (const float*)d_in[0];
  const float* edge_data = (const float*)d_in[1];
  const int*   edges     = (const int*)d_in[2];
  // d_in[3] = T (always 8; hard-coded)
  const float* W1   = (const float*)d_in[4];
  const float* b1   = (const float*)d_in[5];
  const float* W2   = (const float*)d_in[6];
  const float* b2   = (const float*)d_in[7];
  const float* W_ih = (const float*)d_in[8];
  const float* W_hh = (const float*)d_in[9];
  const float* b_ih = (const float*)d_in[10];
  const float* b_hh = (const float*)d_in[11];

  // Workspace 79.06 MB (< 83.59 MB proven bound from R9's nChunks==1):
  // hidh 25.6M | hidl 25.6M | W2Fh 128K | W2Fl 128K | inc 1.6M | off | cur | msg 25.6M
  char* ws = (char*)d_ws;
  size_t o = 0;
  uint32_t* hidh = (uint32_t*)(ws + o); o += (size_t)N_EDGES * 64 * 2;
  uint32_t* hidl = (uint32_t*)(ws + o); o += (size_t)N_EDGES * 64 * 2;
  uint32_t* W2Fh = (uint32_t*)(ws + o); o += 32768u * 4;
  uint32_t* W2Fl = (uint32_t*)(ws + o); o += 32768u * 4;
  int*      inc  = (int*)(ws + o);      o += (size_t)2 * N_EDGES * 4;
  int*      off  = (int*)(ws + o);      o += (size_t)(N_NODES + 4) * 4;
  int*      cur  = (int*)(ws + o);      o += (size_t)N_NODES * 4;
  float*    msg  = (float*)(ws + o);    o += (size_t)N_EDGES * 32 * 4;
  float*    x    = (float*)d_out;   // iterate x in-place in d_out

  const int n4x = N_NODES * H / 4;  // 400000
  copy4_kernel<<<(n4x + 255) / 256, 256, 0, stream>>>((float4*)x, (const float4*)x_in, n4x);
  hidb_kernel<<<N_EDGES * 32 / 256, 256, 0, stream>>>(edge_data, W1, b1, hidh, hidl);
  w2pack_kernel<<<32768 / 256, 256, 0, stream>>>(W2, W2Fh, W2Fl);

  zero_cur_kernel<<<(N_NODES + 255) / 256, 256, 0, stream>>>(cur);
  count_kernel<<<(N_EDGES + 255) / 256, 256, 0, stream>>>(edges, cur);
  scan_kernel<<<1, 1024, 0, stream>>>(cur, off);
  scatter_kernel<<<(N_EDGES + 255) / 256, 256, 0, stream>>>(edges, cur, inc);

  for (int it = 0; it < T_STEPS; it++) {
    msg_kernel<<<1024, 256, 0, stream>>>(W2Fh, W2Fl, hidh, hidl, b2, x, edges, msg);
    node_kernel<<<N_NODES / 16, 512, 0, stream>>>(x, msg, off, inc,
                                                  W_ih, W_hh, b_ih, b_hh);
  }
}